// Round 9
// baseline (387.507 us; speedup 1.0000x reference)
//
#include <hip/hip_runtime.h>
#include <math.h>

#define N_NODES 100000
#define N_EDGES 1600000
#define IN_DIM  128
#define HD      64     // HEADS * OUT_DIM
#define HEADS   4
#define ODIM    16
#define NEG_SLOPE 0.2f

#define BSH 8                                   // nodes per bucket = 256
#define NB  ((N_NODES + 255) >> 8)              // 391 buckets
#define PART_BLOCKS 256
#define EPB ((N_EDGES + PART_BLOCKS - 1) / PART_BLOCKS)   // 6250
#define MAT (NB * PART_BLOCKS)                  // 100096 = 391 * 256 exactly
#define CAP 12288                               // LDS stage cap per bucket

__device__ inline unsigned short f32_to_bf16_rne(float f) {
    unsigned int b = __float_as_uint(f);
    b += 0x7FFFu + ((b >> 16) & 1u);
    return (unsigned short)(b >> 16);
}
__device__ inline float bf16_to_f32(unsigned short u) {
    return __uint_as_float(((unsigned int)u) << 16);
}

// ---------------------------------------------------------------------------
// Kernel 1: h = feat @ W  + fused el/er epilogue. h stored as bf16.
// ---------------------------------------------------------------------------
__global__ __launch_bounds__(256) void k_gemm_fused(const float* __restrict__ feat,
                                                    const float* __restrict__ W,
                                                    const float* __restrict__ attn_l,
                                                    const float* __restrict__ attn_r,
                                                    unsigned short* __restrict__ hbf,
                                                    float* __restrict__ el,
                                                    float* __restrict__ er) {
    __shared__ float sF[64][IN_DIM];
    __shared__ float sW[IN_DIM][HD];

    const int tid  = threadIdx.x;
    const int base = blockIdx.x * 64;

    for (int i = tid; i < IN_DIM * HD; i += 256) sW[i >> 6][i & 63] = W[i];
    for (int i = tid; i < 64 * IN_DIM; i += 256) {
        int n = i >> 7, k = i & 127;
        int gn = base + n;
        sF[n][k] = (gn < N_NODES) ? feat[gn * IN_DIM + k] : 0.f;
    }
    __syncthreads();

    const int cg = (tid & 15) * 4;
    const int rg = (tid >> 4) * 4;

    float acc[4][4] = {};
    for (int k = 0; k < IN_DIM; k += 4) {
        float4 w0 = *(const float4*)&sW[k + 0][cg];
        float4 w1 = *(const float4*)&sW[k + 1][cg];
        float4 w2 = *(const float4*)&sW[k + 2][cg];
        float4 w3 = *(const float4*)&sW[k + 3][cg];
        #pragma unroll
        for (int r = 0; r < 4; ++r) {
            float4 f = *(const float4*)&sF[rg + r][k];
            acc[r][0] += f.x * w0.x + f.y * w1.x + f.z * w2.x + f.w * w3.x;
            acc[r][1] += f.x * w0.y + f.y * w1.y + f.z * w2.y + f.w * w3.y;
            acc[r][2] += f.x * w0.z + f.y * w1.z + f.z * w2.z + f.w * w3.z;
            acc[r][3] += f.x * w0.w + f.y * w1.w + f.z * w2.w + f.w * w3.w;
        }
    }

    #pragma unroll
    for (int r = 0; r < 4; ++r) {
        int gn = base + rg + r;
        if (gn < N_NODES) {
            ushort4 v;
            v.x = f32_to_bf16_rne(acc[r][0]);
            v.y = f32_to_bf16_rne(acc[r][1]);
            v.z = f32_to_bf16_rne(acc[r][2]);
            v.w = f32_to_bf16_rne(acc[r][3]);
            *(ushort4*)&hbf[gn * HD + cg] = v;
        }
    }

    float4 al = *(const float4*)&attn_l[cg];
    float4 ar = *(const float4*)&attn_r[cg];
    const int head = (tid & 15) >> 2;
    #pragma unroll
    for (int r = 0; r < 4; ++r) {
        float pl = acc[r][0]*al.x + acc[r][1]*al.y + acc[r][2]*al.z + acc[r][3]*al.w;
        float pr = acc[r][0]*ar.x + acc[r][1]*ar.y + acc[r][2]*ar.z + acc[r][3]*ar.w;
        pl += __shfl_xor(pl, 1); pl += __shfl_xor(pl, 2);
        pr += __shfl_xor(pr, 1); pr += __shfl_xor(pr, 2);
        int gn = base + rg + r;
        if ((tid & 3) == 0 && gn < N_NODES) {
            el[gn * HEADS + head] = pl;
            er[gn * HEADS + head] = pr;
        }
    }
}

// ---------------------------------------------------------------------------
// CSR build, two-level counting sort.
// ---------------------------------------------------------------------------
__global__ __launch_bounds__(256) void k_count(const int* __restrict__ dst,
                                               int* __restrict__ counts) {
    __shared__ int h[NB];
    for (int i = threadIdx.x; i < NB; i += 256) h[i] = 0;
    __syncthreads();
    int beg = blockIdx.x * EPB;
    int end = beg + EPB; if (end > N_EDGES) end = N_EDGES;
    for (int e = beg + threadIdx.x; e < end; e += 256)
        atomicAdd(&h[dst[e] >> BSH], 1);
    __syncthreads();
    for (int i = threadIdx.x; i < NB; i += 256)
        counts[i * PART_BLOCKS + blockIdx.x] = h[i];   // bucket-major
}

// scanA: per-bucket-row (256 entries) local exclusive scan + row sums.
// Note row-local excl at col 0 is 0, so bucket base offset lives purely in
// bsums after scanB — consumers add bsums[bucket] directly (no scanC pass).
__global__ __launch_bounds__(256) void k_scanA(int* __restrict__ counts,
                                               int* __restrict__ bsums) {
    __shared__ int wsum[4];
    const int t = threadIdx.x;
    const int i = blockIdx.x * 256 + t;
    const int lane = t & 63, wv = t >> 6;
    int v = counts[i];
    int x = v;
    #pragma unroll
    for (int o = 1; o < 64; o <<= 1) {
        int u = __shfl_up(x, o);
        if (lane >= o) x += u;
    }
    if (lane == 63) wsum[wv] = x;
    __syncthreads();
    if (t == 0) {
        int r = 0;
        #pragma unroll
        for (int w = 0; w < 4; ++w) { int u = wsum[w]; wsum[w] = r; r += u; }
    }
    __syncthreads();
    int excl = x - v + wsum[wv];
    counts[i] = excl;
    if (t == 255) bsums[blockIdx.x] = excl + v;
}

__global__ __launch_bounds__(512) void k_scanB(int* __restrict__ bsums) {
    __shared__ int s[512];
    const int t = threadIdx.x;
    int v = (t < NB) ? bsums[t] : 0;
    s[t] = v;
    __syncthreads();
    for (int o = 1; o < 512; o <<= 1) {
        int u = (t >= o) ? s[t - o] : 0;
        __syncthreads();
        s[t] += u;
        __syncthreads();
    }
    if (t < NB) bsums[t] = s[t] - v;   // exclusive
}

// Level-1 place: cursor = bucket-local offset + bucket base (bsums folded in)
__global__ __launch_bounds__(256) void k_partition(const int* __restrict__ src,
                                                   const int* __restrict__ dst,
                                                   const int* __restrict__ offs,
                                                   const int* __restrict__ bsums,
                                                   int* __restrict__ edges) {
    __shared__ int cur[NB];
    for (int i = threadIdx.x; i < NB; i += 256)
        cur[i] = offs[i * PART_BLOCKS + blockIdx.x] + bsums[i];
    __syncthreads();
    int beg = blockIdx.x * EPB;
    int end = beg + EPB; if (end > N_EDGES) end = N_EDGES;
    for (int e = beg + threadIdx.x; e < end; e += 256) {
        int d = dst[e];
        int pos = atomicAdd(&cur[d >> BSH], 1);
        edges[pos] = (int)(((unsigned)(d & 255) << 24) | (unsigned)src[e]);
    }
}

// Level 2: in-place bucket sort; bucket bounds come straight from bsums.
__global__ __launch_bounds__(256) void k_bucket_sort(const int* __restrict__ bsums,
                                                     int* __restrict__ edges,
                                                     int* __restrict__ deg_g,
                                                     int* __restrict__ cend_g) {
    __shared__ int stage[CAP];
    __shared__ int cnt[256];
    __shared__ int pos[256];
    __shared__ int wsum[4];
    const int b = blockIdx.x;
    const int t = threadIdx.x;
    const int base = bsums[b];
    const int bend = (b + 1 < NB) ? bsums[b + 1] : N_EDGES;
    int n = bend - base;
    if (n > CAP) n = CAP;

    for (int i = t; i < n; i += 256) stage[i] = edges[base + i];
    cnt[t] = 0;
    __syncthreads();
    for (int i = t; i < n; i += 256)
        atomicAdd(&cnt[((unsigned)stage[i]) >> 24], 1);
    __syncthreads();

    const int lane = t & 63, wv = t >> 6;
    int v = cnt[t];
    int x = v;
    #pragma unroll
    for (int o = 1; o < 64; o <<= 1) {
        int u = __shfl_up(x, o);
        if (lane >= o) x += u;
    }
    if (lane == 63) wsum[wv] = x;
    __syncthreads();
    if (t == 0) {
        int r = 0;
        #pragma unroll
        for (int w = 0; w < 4; ++w) { int u = wsum[w]; wsum[w] = r; r += u; }
    }
    __syncthreads();
    int excl = x - v + wsum[wv];
    pos[t] = excl;
    int node = (b << 8) + t;
    if (node < N_NODES) {
        deg_g[node]  = v;
        cend_g[node] = base + excl + v;
    }
    __syncthreads();

    for (int i = t; i < n; i += 256) {
        int e  = stage[i];
        int p  = atomicAdd(&pos[((unsigned)e) >> 24], 1);
        edges[base + p] = e & 0x00FFFFFF;
    }
}

// ---------------------------------------------------------------------------
// Flash-style softmax+aggregate, 8 NODES PER WAVE interleaved.
// ---------------------------------------------------------------------------
#define NPW 8   // nodes per wave
__global__ __launch_bounds__(256) void k_aggregate_csr(
        const int* __restrict__ sorted_src,
        const int* __restrict__ cursor_end,
        const int* __restrict__ deg,
        const unsigned short* __restrict__ hbf,
        const float* __restrict__ el,
        const float* __restrict__ er,
        const float* __restrict__ bias,
        float* __restrict__ out) {
    const int wave = threadIdx.x >> 6;
    const int lane = threadIdx.x & 63;
    const int n0   = (blockIdx.x * 4 + wave) * NPW;
    if (n0 >= N_NODES) return;

    const int h1   = lane & 3;
    const int slot = lane >> 2;
    const int hc   = lane >> 4;

    int   endv[NPW], j0[NPW];
    float er1[NPW];
    float m_p[NPW], l_p[NPW], m_c[NPW];
    float acc0[NPW], acc1[NPW];

    #pragma unroll
    for (int k = 0; k < NPW; ++k) {
        int nk = n0 + k;
        bool ok = nk < N_NODES;
        endv[k] = ok ? cursor_end[nk] : 0;
        int dn  = ok ? deg[nk] : 0;
        j0[k]   = endv[k] - dn;
        er1[k]  = ok ? er[nk * HEADS + h1] : 0.f;
        m_p[k] = -1e30f; l_p[k] = 0.f; m_c[k] = -1e30f;
        acc0[k] = 0.f; acc1[k] = 0.f;
    }

    for (;;) {
        bool any = false;
        #pragma unroll
        for (int k = 0; k < NPW; ++k) any |= (j0[k] < endv[k]);
        if (!any) break;

        int   sK[NPW];
        float xK[NPW];
        // stage A: issue all sorted_src loads
        #pragma unroll
        for (int k = 0; k < NPW; ++k) {
            int j = j0[k] + slot;
            sK[k] = (j0[k] < endv[k] && j < endv[k]) ? sorted_src[j] : -1;
        }
        // stage B: issue all el gathers
        #pragma unroll
        for (int k = 0; k < NPW; ++k) {
            if (sK[k] >= 0) {
                float t = el[sK[k] * HEADS + h1] + er1[k];
                xK[k] = t > 0.f ? t : NEG_SLOPE * t;
            } else {
                xK[k] = -1e30f;
            }
        }
        // stage C: per-node shfl reductions (independent chains)
        float pK[NPW];
        #pragma unroll
        for (int k = 0; k < NPW; ++k) {
            if (j0[k] >= endv[k]) { pK[k] = 0.f; continue; }
            float cm = xK[k];
            cm = fmaxf(cm, __shfl_xor(cm, 4));
            cm = fmaxf(cm, __shfl_xor(cm, 8));
            cm = fmaxf(cm, __shfl_xor(cm, 16));
            cm = fmaxf(cm, __shfl_xor(cm, 32));
            float newm = fmaxf(m_p[k], cm);
            float p = __expf(xK[k] - newm);
            float cs = p;
            cs += __shfl_xor(cs, 4);
            cs += __shfl_xor(cs, 8);
            cs += __shfl_xor(cs, 16);
            cs += __shfl_xor(cs, 32);
            l_p[k] = l_p[k] * __expf(m_p[k] - newm) + cs;
            m_p[k] = newm;
            float mc_new = __shfl(m_p[k], hc);
            float rs = __expf(m_c[k] - mc_new);
            acc0[k] *= rs; acc1[k] *= rs;
            m_c[k] = mc_new;
            pK[k] = p;
        }
        // stage D: per-node gather+fma (2 acc chains each)
        #pragma unroll
        for (int k = 0; k < NPW; ++k) {
            if (j0[k] >= endv[k]) continue;
            int cnt = endv[k] - j0[k]; if (cnt > 16) cnt = 16;
            for (int e = 0; e < cnt; e += 2) {
                float pe0 = __shfl(pK[k], e * 4 + hc);
                int   se0 = __shfl(sK[k], e * 4);
                acc0[k] = fmaf(pe0, bf16_to_f32(hbf[se0 * HD + lane]), acc0[k]);
                if (e + 1 < cnt) {
                    float pe1 = __shfl(pK[k], (e + 1) * 4 + hc);
                    int   se1 = __shfl(sK[k], (e + 1) * 4);
                    acc1[k] = fmaf(pe1, bf16_to_f32(hbf[se1 * HD + lane]), acc1[k]);
                }
            }
            j0[k] += 16;
        }
    }

    const float bl = bias[lane];
    #pragma unroll
    for (int k = 0; k < NPW; ++k) {
        int nk = n0 + k;
        if (nk >= N_NODES) continue;
        float l   = __shfl(l_p[k], hc);
        float inv = (l > 0.f) ? 1.f / l : 0.f;
        out[nk * HD + lane] = (acc0[k] + acc1[k]) * inv + bl;
    }
}

// ---------------------------------------------------------------------------
// Launch
// ---------------------------------------------------------------------------
extern "C" void kernel_launch(void* const* d_in, const int* in_sizes, int n_in,
                              void* d_out, int out_size, void* d_ws, size_t ws_size,
                              hipStream_t stream) {
    const float* feat   = (const float*)d_in[0];
    const float* W      = (const float*)d_in[1];
    const float* attn_l = (const float*)d_in[2];
    const float* attn_r = (const float*)d_in[3];
    const float* bias   = (const float*)d_in[4];
    const int*   src    = (const int*)d_in[5];
    const int*   dst    = (const int*)d_in[6];
    float* out = (float*)d_out;

    // ws (~22 MB): hbf [N*64 bf16] | el [N*4 f32] | er [N*4] | deg [N] | cend [N]
    //              | edges [E] | counts [MAT] | bsums [NB]
    unsigned short* hbf = (unsigned short*)d_ws;
    float* el    = (float*)(hbf + (size_t)N_NODES * HD);
    float* er    = el + (size_t)N_NODES * HEADS;
    int*   deg    = (int*)(er + (size_t)N_NODES * HEADS);
    int*   cend   = deg + N_NODES;
    int*   edges  = cend + N_NODES;
    int*   counts = edges + N_EDGES;
    int*   bsums  = counts + MAT;

    // 1) projection + fused el/er (h stored bf16)
    k_gemm_fused<<<(N_NODES + 63) / 64, 256, 0, stream>>>(feat, W, attn_l, attn_r,
                                                          hbf, el, er);
    // 2) CSR build: two-level counting sort (scanC folded into consumers)
    k_count<<<PART_BLOCKS, 256, 0, stream>>>(dst, counts);
    k_scanA<<<NB, 256, 0, stream>>>(counts, bsums);
    k_scanB<<<1, 512, 0, stream>>>(bsums);
    k_partition<<<PART_BLOCKS, 256, 0, stream>>>(src, dst, counts, bsums, edges);
    k_bucket_sort<<<NB, 256, 0, stream>>>(bsums, edges, deg, cend);
    // 3) fused softmax + aggregation, 8 nodes per wave
    const int nodes_per_block = 4 * NPW;   // 4 waves x 8 nodes
    k_aggregate_csr<<<(N_NODES + nodes_per_block - 1) / nodes_per_block, 256, 0, stream>>>(
        edges, cend, deg, hbf, el, er, bias, out);
}

// Round 10
// 306.500 us; speedup vs baseline: 1.2643x; 1.2643x over previous
//
#include <hip/hip_runtime.h>
#include <math.h>

#define N_NODES 100000
#define N_EDGES 1600000
#define IN_DIM  128
#define HD      64     // HEADS * OUT_DIM
#define HEADS   4
#define ODIM    16
#define NEG_SLOPE 0.2f

#define BSH 8                                   // nodes per bucket = 256
#define NB  ((N_NODES + 255) >> 8)              // 391 buckets
#define PART_BLOCKS 256
#define EPB ((N_EDGES + PART_BLOCKS - 1) / PART_BLOCKS)   // 6250
#define MAT (NB * PART_BLOCKS)                  // 100096 = 391 * 256 exactly
#define CAP 12288                               // LDS stage cap per bucket

__device__ inline unsigned short f32_to_bf16_rne(float f) {
    unsigned int b = __float_as_uint(f);
    b += 0x7FFFu + ((b >> 16) & 1u);
    return (unsigned short)(b >> 16);
}
__device__ inline float bf16_to_f32(unsigned short u) {
    return __uint_as_float(((unsigned int)u) << 16);
}

// ---------------------------------------------------------------------------
// Kernel 1: h = feat @ W  + fused el/er epilogue. h stored as bf16.
// ---------------------------------------------------------------------------
__global__ __launch_bounds__(256) void k_gemm_fused(const float* __restrict__ feat,
                                                    const float* __restrict__ W,
                                                    const float* __restrict__ attn_l,
                                                    const float* __restrict__ attn_r,
                                                    unsigned short* __restrict__ hbf,
                                                    float* __restrict__ el,
                                                    float* __restrict__ er) {
    __shared__ float sF[64][IN_DIM];
    __shared__ float sW[IN_DIM][HD];

    const int tid  = threadIdx.x;
    const int base = blockIdx.x * 64;

    for (int i = tid; i < IN_DIM * HD; i += 256) sW[i >> 6][i & 63] = W[i];
    for (int i = tid; i < 64 * IN_DIM; i += 256) {
        int n = i >> 7, k = i & 127;
        int gn = base + n;
        sF[n][k] = (gn < N_NODES) ? feat[gn * IN_DIM + k] : 0.f;
    }
    __syncthreads();

    const int cg = (tid & 15) * 4;
    const int rg = (tid >> 4) * 4;

    float acc[4][4] = {};
    for (int k = 0; k < IN_DIM; k += 4) {
        float4 w0 = *(const float4*)&sW[k + 0][cg];
        float4 w1 = *(const float4*)&sW[k + 1][cg];
        float4 w2 = *(const float4*)&sW[k + 2][cg];
        float4 w3 = *(const float4*)&sW[k + 3][cg];
        #pragma unroll
        for (int r = 0; r < 4; ++r) {
            float4 f = *(const float4*)&sF[rg + r][k];
            acc[r][0] += f.x * w0.x + f.y * w1.x + f.z * w2.x + f.w * w3.x;
            acc[r][1] += f.x * w0.y + f.y * w1.y + f.z * w2.y + f.w * w3.y;
            acc[r][2] += f.x * w0.z + f.y * w1.z + f.z * w2.z + f.w * w3.z;
            acc[r][3] += f.x * w0.w + f.y * w1.w + f.z * w2.w + f.w * w3.w;
        }
    }

    #pragma unroll
    for (int r = 0; r < 4; ++r) {
        int gn = base + rg + r;
        if (gn < N_NODES) {
            ushort4 v;
            v.x = f32_to_bf16_rne(acc[r][0]);
            v.y = f32_to_bf16_rne(acc[r][1]);
            v.z = f32_to_bf16_rne(acc[r][2]);
            v.w = f32_to_bf16_rne(acc[r][3]);
            *(ushort4*)&hbf[gn * HD + cg] = v;
        }
    }

    float4 al = *(const float4*)&attn_l[cg];
    float4 ar = *(const float4*)&attn_r[cg];
    const int head = (tid & 15) >> 2;
    #pragma unroll
    for (int r = 0; r < 4; ++r) {
        float pl = acc[r][0]*al.x + acc[r][1]*al.y + acc[r][2]*al.z + acc[r][3]*al.w;
        float pr = acc[r][0]*ar.x + acc[r][1]*ar.y + acc[r][2]*ar.z + acc[r][3]*ar.w;
        pl += __shfl_xor(pl, 1); pl += __shfl_xor(pl, 2);
        pr += __shfl_xor(pr, 1); pr += __shfl_xor(pr, 2);
        int gn = base + rg + r;
        if ((tid & 3) == 0 && gn < N_NODES) {
            el[gn * HEADS + head] = pl;
            er[gn * HEADS + head] = pr;
        }
    }
}

// ---------------------------------------------------------------------------
// CSR build, two-level counting sort (scanC folded into consumers).
// ---------------------------------------------------------------------------
__global__ __launch_bounds__(256) void k_count(const int* __restrict__ dst,
                                               int* __restrict__ counts) {
    __shared__ int h[NB];
    for (int i = threadIdx.x; i < NB; i += 256) h[i] = 0;
    __syncthreads();
    int beg = blockIdx.x * EPB;
    int end = beg + EPB; if (end > N_EDGES) end = N_EDGES;
    for (int e = beg + threadIdx.x; e < end; e += 256)
        atomicAdd(&h[dst[e] >> BSH], 1);
    __syncthreads();
    for (int i = threadIdx.x; i < NB; i += 256)
        counts[i * PART_BLOCKS + blockIdx.x] = h[i];   // bucket-major
}

__global__ __launch_bounds__(256) void k_scanA(int* __restrict__ counts,
                                               int* __restrict__ bsums) {
    __shared__ int wsum[4];
    const int t = threadIdx.x;
    const int i = blockIdx.x * 256 + t;
    const int lane = t & 63, wv = t >> 6;
    int v = counts[i];
    int x = v;
    #pragma unroll
    for (int o = 1; o < 64; o <<= 1) {
        int u = __shfl_up(x, o);
        if (lane >= o) x += u;
    }
    if (lane == 63) wsum[wv] = x;
    __syncthreads();
    if (t == 0) {
        int r = 0;
        #pragma unroll
        for (int w = 0; w < 4; ++w) { int u = wsum[w]; wsum[w] = r; r += u; }
    }
    __syncthreads();
    int excl = x - v + wsum[wv];
    counts[i] = excl;
    if (t == 255) bsums[blockIdx.x] = excl + v;
}

__global__ __launch_bounds__(512) void k_scanB(int* __restrict__ bsums) {
    __shared__ int s[512];
    const int t = threadIdx.x;
    int v = (t < NB) ? bsums[t] : 0;
    s[t] = v;
    __syncthreads();
    for (int o = 1; o < 512; o <<= 1) {
        int u = (t >= o) ? s[t - o] : 0;
        __syncthreads();
        s[t] += u;
        __syncthreads();
    }
    if (t < NB) bsums[t] = s[t] - v;   // exclusive
}

__global__ __launch_bounds__(256) void k_partition(const int* __restrict__ src,
                                                   const int* __restrict__ dst,
                                                   const int* __restrict__ offs,
                                                   const int* __restrict__ bsums,
                                                   int* __restrict__ edges) {
    __shared__ int cur[NB];
    for (int i = threadIdx.x; i < NB; i += 256)
        cur[i] = offs[i * PART_BLOCKS + blockIdx.x] + bsums[i];
    __syncthreads();
    int beg = blockIdx.x * EPB;
    int end = beg + EPB; if (end > N_EDGES) end = N_EDGES;
    for (int e = beg + threadIdx.x; e < end; e += 256) {
        int d = dst[e];
        int pos = atomicAdd(&cur[d >> BSH], 1);
        edges[pos] = (int)(((unsigned)(d & 255) << 24) | (unsigned)src[e]);
    }
}

__global__ __launch_bounds__(256) void k_bucket_sort(const int* __restrict__ bsums,
                                                     int* __restrict__ edges,
                                                     int* __restrict__ deg_g,
                                                     int* __restrict__ cend_g) {
    __shared__ int stage[CAP];
    __shared__ int cnt[256];
    __shared__ int pos[256];
    __shared__ int wsum[4];
    const int b = blockIdx.x;
    const int t = threadIdx.x;
    const int base = bsums[b];
    const int bend = (b + 1 < NB) ? bsums[b + 1] : N_EDGES;
    int n = bend - base;
    if (n > CAP) n = CAP;

    for (int i = t; i < n; i += 256) stage[i] = edges[base + i];
    cnt[t] = 0;
    __syncthreads();
    for (int i = t; i < n; i += 256)
        atomicAdd(&cnt[((unsigned)stage[i]) >> 24], 1);
    __syncthreads();

    const int lane = t & 63, wv = t >> 6;
    int v = cnt[t];
    int x = v;
    #pragma unroll
    for (int o = 1; o < 64; o <<= 1) {
        int u = __shfl_up(x, o);
        if (lane >= o) x += u;
    }
    if (lane == 63) wsum[wv] = x;
    __syncthreads();
    if (t == 0) {
        int r = 0;
        #pragma unroll
        for (int w = 0; w < 4; ++w) { int u = wsum[w]; wsum[w] = r; r += u; }
    }
    __syncthreads();
    int excl = x - v + wsum[wv];
    pos[t] = excl;
    int node = (b << 8) + t;
    if (node < N_NODES) {
        deg_g[node]  = v;
        cend_g[node] = base + excl + v;
    }
    __syncthreads();

    for (int i = t; i < n; i += 256) {
        int e  = stage[i];
        int p  = atomicAdd(&pos[((unsigned)e) >> 24], 1);
        edges[base + p] = e & 0x00FFFFFF;
    }
}

// ---------------------------------------------------------------------------
// Flash-style softmax+aggregate, 4 nodes/wave (NPW=8 spilled — reverted).
// Stage D uses pair-edge ushort2 gathers: lane = (g=lane>>5, c=lane&31);
// lane loads cols {2c,2c+1} (one uint) of edge 2t+g -> one load instruction
// covers two full 128B rows; 2 shfls per 2 edges instead of 4.
// Epilogue: even/odd-edge halves combined via shfl_xor(32); lanes 0-31
// write coalesced float2.
// ---------------------------------------------------------------------------
#define NPW 4   // nodes per wave
__global__ __launch_bounds__(256) void k_aggregate_csr(
        const int* __restrict__ sorted_src,
        const int* __restrict__ cursor_end,
        const int* __restrict__ deg,
        const unsigned short* __restrict__ hbf,
        const float* __restrict__ el,
        const float* __restrict__ er,
        const float* __restrict__ bias,
        float* __restrict__ out) {
    const int wave = threadIdx.x >> 6;
    const int lane = threadIdx.x & 63;
    const int n0   = (blockIdx.x * 4 + wave) * NPW;
    if (n0 >= N_NODES) return;

    const int h1   = lane & 3;     // producer head
    const int slot = lane >> 2;    // producer edge slot (0..15)
    const int g    = lane >> 5;    // consumer edge-pair group (0/1)
    const int c    = lane & 31;    // consumer column-pair index (cols 2c,2c+1)
    const int hd   = c >> 3;       // head of cols 2c,2c+1

    int   endv[NPW], j0[NPW];
    float er1[NPW];
    float m_p[NPW], l_p[NPW], m_c[NPW];
    float accL[NPW], accH[NPW];

    #pragma unroll
    for (int k = 0; k < NPW; ++k) {
        int nk = n0 + k;
        bool ok = nk < N_NODES;
        endv[k] = ok ? cursor_end[nk] : 0;
        int dn  = ok ? deg[nk] : 0;
        j0[k]   = endv[k] - dn;
        er1[k]  = ok ? er[nk * HEADS + h1] : 0.f;
        m_p[k] = -1e30f; l_p[k] = 0.f; m_c[k] = -1e30f;
        accL[k] = 0.f; accH[k] = 0.f;
    }

    for (;;) {
        bool any = false;
        #pragma unroll
        for (int k = 0; k < NPW; ++k) any |= (j0[k] < endv[k]);
        if (!any) break;

        int   sK[NPW];
        float xK[NPW];
        // stage A: issue all sorted_src loads
        #pragma unroll
        for (int k = 0; k < NPW; ++k) {
            int j = j0[k] + slot;
            sK[k] = (j0[k] < endv[k] && j < endv[k]) ? sorted_src[j] : -1;
        }
        // stage B: issue all el gathers
        #pragma unroll
        for (int k = 0; k < NPW; ++k) {
            if (sK[k] >= 0) {
                float t = el[sK[k] * HEADS + h1] + er1[k];
                xK[k] = t > 0.f ? t : NEG_SLOPE * t;
            } else {
                xK[k] = -1e30f;
            }
        }
        // stage C: per-node shfl reductions (independent chains)
        float pK[NPW];
        #pragma unroll
        for (int k = 0; k < NPW; ++k) {
            if (j0[k] >= endv[k]) { pK[k] = 0.f; continue; }
            float cm = xK[k];
            cm = fmaxf(cm, __shfl_xor(cm, 4));
            cm = fmaxf(cm, __shfl_xor(cm, 8));
            cm = fmaxf(cm, __shfl_xor(cm, 16));
            cm = fmaxf(cm, __shfl_xor(cm, 32));
            float newm = fmaxf(m_p[k], cm);
            float p = __expf(xK[k] - newm);      // invalid slots -> 0
            float cs = p;
            cs += __shfl_xor(cs, 4);
            cs += __shfl_xor(cs, 8);
            cs += __shfl_xor(cs, 16);
            cs += __shfl_xor(cs, 32);
            l_p[k] = l_p[k] * __expf(m_p[k] - newm) + cs;
            m_p[k] = newm;
            float mc_new = __shfl(m_p[k], hd);
            float rs = __expf(m_c[k] - mc_new);
            accL[k] *= rs; accH[k] *= rs;
            m_c[k] = mc_new;
            pK[k] = p;
        }
        // stage D: pair-edge gathers, 2 bf16 cols per lane per step
        #pragma unroll
        for (int k = 0; k < NPW; ++k) {
            if (j0[k] >= endv[k]) continue;
            int cnt = endv[k] - j0[k]; if (cnt > 16) cnt = 16;
            int steps = (cnt + 1) >> 1;
            for (int t = 0; t < steps; ++t) {
                int e = 2 * t + g;                        // this group's edge
                float pe = __shfl(pK[k], e * 4 + hd);     // 0 for invalid edge
                int   se = __shfl(sK[k], e * 4);
                unsigned row = (se < 0) ? 0u : (unsigned)se;
                unsigned u = *(const unsigned*)&hbf[row * HD + 2 * c];
                accL[k] = fmaf(pe, bf16_to_f32((unsigned short)(u & 0xffffu)), accL[k]);
                accH[k] = fmaf(pe, bf16_to_f32((unsigned short)(u >> 16)),     accH[k]);
            }
            j0[k] += 16;
        }
    }

    const float2 bl = ((const float2*)bias)[c];
    #pragma unroll
    for (int k = 0; k < NPW; ++k) {
        int nk = n0 + k;
        if (nk >= N_NODES) continue;
        float l   = __shfl(l_p[k], hd);
        float inv = (l > 0.f) ? 1.f / l : 0.f;
        float vL = accL[k] + __shfl_xor(accL[k], 32);
        float vH = accH[k] + __shfl_xor(accH[k], 32);
        if (lane < 32) {
            float2 v = make_float2(vL * inv + bl.x, vH * inv + bl.y);
            *(float2*)&out[nk * HD + 2 * c] = v;
        }
    }
}

// ---------------------------------------------------------------------------
// Launch
// ---------------------------------------------------------------------------
extern "C" void kernel_launch(void* const* d_in, const int* in_sizes, int n_in,
                              void* d_out, int out_size, void* d_ws, size_t ws_size,
                              hipStream_t stream) {
    const float* feat   = (const float*)d_in[0];
    const float* W      = (const float*)d_in[1];
    const float* attn_l = (const float*)d_in[2];
    const float* attn_r = (const float*)d_in[3];
    const float* bias   = (const float*)d_in[4];
    const int*   src    = (const int*)d_in[5];
    const int*   dst    = (const int*)d_in[6];
    float* out = (float*)d_out;

    // ws (~22 MB): hbf [N*64 bf16] | el [N*4 f32] | er [N*4] | deg [N] | cend [N]
    //              | edges [E] | counts [MAT] | bsums [NB]
    unsigned short* hbf = (unsigned short*)d_ws;
    float* el    = (float*)(hbf + (size_t)N_NODES * HD);
    float* er    = el + (size_t)N_NODES * HEADS;
    int*   deg    = (int*)(er + (size_t)N_NODES * HEADS);
    int*   cend   = deg + N_NODES;
    int*   edges  = cend + N_NODES;
    int*   counts = edges + N_EDGES;
    int*   bsums  = counts + MAT;

    // 1) projection + fused el/er (h stored bf16)
    k_gemm_fused<<<(N_NODES + 63) / 64, 256, 0, stream>>>(feat, W, attn_l, attn_r,
                                                          hbf, el, er);
    // 2) CSR build: two-level counting sort (scanC folded into consumers)
    k_count<<<PART_BLOCKS, 256, 0, stream>>>(dst, counts);
    k_scanA<<<NB, 256, 0, stream>>>(counts, bsums);
    k_scanB<<<1, 512, 0, stream>>>(bsums);
    k_partition<<<PART_BLOCKS, 256, 0, stream>>>(src, dst, counts, bsums, edges);
    k_bucket_sort<<<NB, 256, 0, stream>>>(bsums, edges, deg, cend);
    // 3) fused softmax + aggregation, 4 nodes per wave
    const int nodes_per_block = 4 * NPW;   // 4 waves x 4 nodes
    k_aggregate_csr<<<(N_NODES + nodes_per_block - 1) / nodes_per_block, 256, 0, stream>>>(
        edges, cend, deg, hbf, el, er, bias, out);
}

// Round 11
// 261.272 us; speedup vs baseline: 1.4832x; 1.1731x over previous
//
#include <hip/hip_runtime.h>
#include <math.h>

#define N_NODES 100000
#define N_EDGES 1600000
#define IN_DIM  128
#define HD      64     // HEADS * OUT_DIM
#define HEADS   4
#define ODIM    16
#define NEG_SLOPE 0.2f

#define BSH 8                                   // nodes per bucket = 256
#define NB  ((N_NODES + 255) >> 8)              // 391 buckets
#define PART_BLOCKS 256
#define EPB ((N_EDGES + PART_BLOCKS - 1) / PART_BLOCKS)   // 6250
#define MAT (NB * PART_BLOCKS)                  // 100096 = 391 * 256 exactly
#define CAP 12288                               // LDS stage cap per bucket

__device__ inline unsigned short f32_to_bf16_rne(float f) {
    unsigned int b = __float_as_uint(f);
    b += 0x7FFFu + ((b >> 16) & 1u);
    return (unsigned short)(b >> 16);
}
__device__ inline float bf16_to_f32(unsigned short u) {
    return __uint_as_float(((unsigned int)u) << 16);
}

// ---------------------------------------------------------------------------
// Kernel 1: h = feat @ W + fused el/er. 128 nodes x 64 cols per block,
// 8x4 register tile, K in 4 chunks of 32 staged as transposed sFT[32][132]
// (stride 132: 16B-aligned rows, conflict-free reads) + sW[32][64].
// LDS 24.5 KB -> ~6 blocks/CU (was 64 KB -> 2).
// ---------------------------------------------------------------------------
__global__ __launch_bounds__(256) void k_gemm_fused(const float* __restrict__ feat,
                                                    const float* __restrict__ W,
                                                    const float* __restrict__ attn_l,
                                                    const float* __restrict__ attn_r,
                                                    unsigned short* __restrict__ hbf,
                                                    float* __restrict__ el,
                                                    float* __restrict__ er) {
    __shared__ float sFT[32][132];   // [k][node] for 128 nodes (+4 pad)
    __shared__ float sW[32][64];     // [k][col]

    const int tid  = threadIdx.x;
    const int nid  = tid >> 4;       // 0..15: node group (8 nodes)
    const int cid  = tid & 15;       // 0..15: col group (4 cols)
    const int c0   = cid * 4;
    const int nblk = blockIdx.x * 128;

    // staging mapping: 128 lanes-worth of rows, 2 k-quarters
    const int ln  = tid & 127;       // node within block
    const int lkq = tid >> 7;        // 0/1: k-quarter of 16

    float acc[8][4] = {};

    for (int kc = 0; kc < 4; ++kc) {
        const int k0 = kc * 32;
        // stage feat chunk transposed
        const int gn = nblk + ln;
        #pragma unroll
        for (int i = 0; i < 4; ++i) {
            float4 v = (gn < N_NODES)
                ? *(const float4*)&feat[(size_t)gn * IN_DIM + k0 + lkq * 16 + i * 4]
                : make_float4(0.f, 0.f, 0.f, 0.f);
            const int kk = lkq * 16 + i * 4;
            sFT[kk + 0][ln] = v.x;
            sFT[kk + 1][ln] = v.y;
            sFT[kk + 2][ln] = v.z;
            sFT[kk + 3][ln] = v.w;
        }
        // stage W chunk (32 rows x 64 cols = 512 float4)
        {
            const float4* W4 = (const float4*)(W + k0 * HD);
            float4 a = W4[tid];
            float4 b = W4[tid + 256];
            ((float4*)&sW[0][0])[tid]       = a;
            ((float4*)&sW[0][0])[tid + 256] = b;
        }
        __syncthreads();

        #pragma unroll 8
        for (int k = 0; k < 32; ++k) {
            float4 w  = *(const float4*)&sW[k][c0];
            float4 fA = *(const float4*)&sFT[k][nid * 8];
            float4 fB = *(const float4*)&sFT[k][nid * 8 + 4];
            float fr[8] = {fA.x, fA.y, fA.z, fA.w, fB.x, fB.y, fB.z, fB.w};
            #pragma unroll
            for (int r = 0; r < 8; ++r) {
                acc[r][0] = fmaf(fr[r], w.x, acc[r][0]);
                acc[r][1] = fmaf(fr[r], w.y, acc[r][1]);
                acc[r][2] = fmaf(fr[r], w.z, acc[r][2]);
                acc[r][3] = fmaf(fr[r], w.w, acc[r][3]);
            }
        }
        __syncthreads();
    }

    // epilogue: bf16 store + fused el/er (reduce over 4 cid lanes per head)
    float4 al = *(const float4*)&attn_l[c0];
    float4 ar = *(const float4*)&attn_r[c0];
    const int head = cid >> 2;
    #pragma unroll
    for (int r = 0; r < 8; ++r) {
        int gn = nblk + nid * 8 + r;
        float pl = acc[r][0]*al.x + acc[r][1]*al.y + acc[r][2]*al.z + acc[r][3]*al.w;
        float pr = acc[r][0]*ar.x + acc[r][1]*ar.y + acc[r][2]*ar.z + acc[r][3]*ar.w;
        pl += __shfl_xor(pl, 1); pl += __shfl_xor(pl, 2);
        pr += __shfl_xor(pr, 1); pr += __shfl_xor(pr, 2);
        if (gn < N_NODES) {
            ushort4 hv;
            hv.x = f32_to_bf16_rne(acc[r][0]);
            hv.y = f32_to_bf16_rne(acc[r][1]);
            hv.z = f32_to_bf16_rne(acc[r][2]);
            hv.w = f32_to_bf16_rne(acc[r][3]);
            *(ushort4*)&hbf[(size_t)gn * HD + c0] = hv;
            if ((cid & 3) == 0) {
                el[gn * HEADS + head] = pl;
                er[gn * HEADS + head] = pr;
            }
        }
    }
}

// ---------------------------------------------------------------------------
// CSR build, two-level counting sort (scanC folded into consumers).
// ---------------------------------------------------------------------------
__global__ __launch_bounds__(256) void k_count(const int* __restrict__ dst,
                                               int* __restrict__ counts) {
    __shared__ int h[NB];
    for (int i = threadIdx.x; i < NB; i += 256) h[i] = 0;
    __syncthreads();
    int beg = blockIdx.x * EPB;
    int end = beg + EPB; if (end > N_EDGES) end = N_EDGES;
    for (int e = beg + threadIdx.x; e < end; e += 256)
        atomicAdd(&h[dst[e] >> BSH], 1);
    __syncthreads();
    for (int i = threadIdx.x; i < NB; i += 256)
        counts[i * PART_BLOCKS + blockIdx.x] = h[i];   // bucket-major
}

__global__ __launch_bounds__(256) void k_scanA(int* __restrict__ counts,
                                               int* __restrict__ bsums) {
    __shared__ int wsum[4];
    const int t = threadIdx.x;
    const int i = blockIdx.x * 256 + t;
    const int lane = t & 63, wv = t >> 6;
    int v = counts[i];
    int x = v;
    #pragma unroll
    for (int o = 1; o < 64; o <<= 1) {
        int u = __shfl_up(x, o);
        if (lane >= o) x += u;
    }
    if (lane == 63) wsum[wv] = x;
    __syncthreads();
    if (t == 0) {
        int r = 0;
        #pragma unroll
        for (int w = 0; w < 4; ++w) { int u = wsum[w]; wsum[w] = r; r += u; }
    }
    __syncthreads();
    int excl = x - v + wsum[wv];
    counts[i] = excl;
    if (t == 255) bsums[blockIdx.x] = excl + v;
}

__global__ __launch_bounds__(512) void k_scanB(int* __restrict__ bsums) {
    __shared__ int s[512];
    const int t = threadIdx.x;
    int v = (t < NB) ? bsums[t] : 0;
    s[t] = v;
    __syncthreads();
    for (int o = 1; o < 512; o <<= 1) {
        int u = (t >= o) ? s[t - o] : 0;
        __syncthreads();
        s[t] += u;
        __syncthreads();
    }
    if (t < NB) bsums[t] = s[t] - v;   // exclusive
}

__global__ __launch_bounds__(256) void k_partition(const int* __restrict__ src,
                                                   const int* __restrict__ dst,
                                                   const int* __restrict__ offs,
                                                   const int* __restrict__ bsums,
                                                   int* __restrict__ edges) {
    __shared__ int cur[NB];
    for (int i = threadIdx.x; i < NB; i += 256)
        cur[i] = offs[i * PART_BLOCKS + blockIdx.x] + bsums[i];
    __syncthreads();
    int beg = blockIdx.x * EPB;
    int end = beg + EPB; if (end > N_EDGES) end = N_EDGES;
    for (int e = beg + threadIdx.x; e < end; e += 256) {
        int d = dst[e];
        int pos = atomicAdd(&cur[d >> BSH], 1);
        edges[pos] = (int)(((unsigned)(d & 255) << 24) | (unsigned)src[e]);
    }
}

__global__ __launch_bounds__(256) void k_bucket_sort(const int* __restrict__ bsums,
                                                     int* __restrict__ edges,
                                                     int* __restrict__ deg_g,
                                                     int* __restrict__ cend_g) {
    __shared__ int stage[CAP];
    __shared__ int cnt[256];
    __shared__ int pos[256];
    __shared__ int wsum[4];
    const int b = blockIdx.x;
    const int t = threadIdx.x;
    const int base = bsums[b];
    const int bend = (b + 1 < NB) ? bsums[b + 1] : N_EDGES;
    int n = bend - base;
    if (n > CAP) n = CAP;

    for (int i = t; i < n; i += 256) stage[i] = edges[base + i];
    cnt[t] = 0;
    __syncthreads();
    for (int i = t; i < n; i += 256)
        atomicAdd(&cnt[((unsigned)stage[i]) >> 24], 1);
    __syncthreads();

    const int lane = t & 63, wv = t >> 6;
    int v = cnt[t];
    int x = v;
    #pragma unroll
    for (int o = 1; o < 64; o <<= 1) {
        int u = __shfl_up(x, o);
        if (lane >= o) x += u;
    }
    if (lane == 63) wsum[wv] = x;
    __syncthreads();
    if (t == 0) {
        int r = 0;
        #pragma unroll
        for (int w = 0; w < 4; ++w) { int u = wsum[w]; wsum[w] = r; r += u; }
    }
    __syncthreads();
    int excl = x - v + wsum[wv];
    pos[t] = excl;
    int node = (b << 8) + t;
    if (node < N_NODES) {
        deg_g[node]  = v;
        cend_g[node] = base + excl + v;
    }
    __syncthreads();

    for (int i = t; i < n; i += 256) {
        int e  = stage[i];
        int p  = atomicAdd(&pos[((unsigned)e) >> 24], 1);
        edges[base + p] = e & 0x00FFFFFF;
    }
}

// ---------------------------------------------------------------------------
// Flash-style softmax+aggregate, 4 nodes/wave, pair-edge ushort2 gathers.
// ---------------------------------------------------------------------------
#define NPW 4   // nodes per wave
__global__ __launch_bounds__(256) void k_aggregate_csr(
        const int* __restrict__ sorted_src,
        const int* __restrict__ cursor_end,
        const int* __restrict__ deg,
        const unsigned short* __restrict__ hbf,
        const float* __restrict__ el,
        const float* __restrict__ er,
        const float* __restrict__ bias,
        float* __restrict__ out) {
    const int wave = threadIdx.x >> 6;
    const int lane = threadIdx.x & 63;
    const int n0   = (blockIdx.x * 4 + wave) * NPW;
    if (n0 >= N_NODES) return;

    const int h1   = lane & 3;     // producer head
    const int slot = lane >> 2;    // producer edge slot (0..15)
    const int g    = lane >> 5;    // consumer edge-pair group (0/1)
    const int c    = lane & 31;    // consumer column-pair index (cols 2c,2c+1)
    const int hd   = c >> 3;       // head of cols 2c,2c+1

    int   endv[NPW], j0[NPW];
    float er1[NPW];
    float m_p[NPW], l_p[NPW], m_c[NPW];
    float accL[NPW], accH[NPW];

    #pragma unroll
    for (int k = 0; k < NPW; ++k) {
        int nk = n0 + k;
        bool ok = nk < N_NODES;
        endv[k] = ok ? cursor_end[nk] : 0;
        int dn  = ok ? deg[nk] : 0;
        j0[k]   = endv[k] - dn;
        er1[k]  = ok ? er[nk * HEADS + h1] : 0.f;
        m_p[k] = -1e30f; l_p[k] = 0.f; m_c[k] = -1e30f;
        accL[k] = 0.f; accH[k] = 0.f;
    }

    for (;;) {
        bool any = false;
        #pragma unroll
        for (int k = 0; k < NPW; ++k) any |= (j0[k] < endv[k]);
        if (!any) break;

        int   sK[NPW];
        float xK[NPW];
        #pragma unroll
        for (int k = 0; k < NPW; ++k) {
            int j = j0[k] + slot;
            sK[k] = (j0[k] < endv[k] && j < endv[k]) ? sorted_src[j] : -1;
        }
        #pragma unroll
        for (int k = 0; k < NPW; ++k) {
            if (sK[k] >= 0) {
                float t = el[sK[k] * HEADS + h1] + er1[k];
                xK[k] = t > 0.f ? t : NEG_SLOPE * t;
            } else {
                xK[k] = -1e30f;
            }
        }
        float pK[NPW];
        #pragma unroll
        for (int k = 0; k < NPW; ++k) {
            if (j0[k] >= endv[k]) { pK[k] = 0.f; continue; }
            float cm = xK[k];
            cm = fmaxf(cm, __shfl_xor(cm, 4));
            cm = fmaxf(cm, __shfl_xor(cm, 8));
            cm = fmaxf(cm, __shfl_xor(cm, 16));
            cm = fmaxf(cm, __shfl_xor(cm, 32));
            float newm = fmaxf(m_p[k], cm);
            float p = __expf(xK[k] - newm);
            float cs = p;
            cs += __shfl_xor(cs, 4);
            cs += __shfl_xor(cs, 8);
            cs += __shfl_xor(cs, 16);
            cs += __shfl_xor(cs, 32);
            l_p[k] = l_p[k] * __expf(m_p[k] - newm) + cs;
            m_p[k] = newm;
            float mc_new = __shfl(m_p[k], hd);
            float rs = __expf(m_c[k] - mc_new);
            accL[k] *= rs; accH[k] *= rs;
            m_c[k] = mc_new;
            pK[k] = p;
        }
        #pragma unroll
        for (int k = 0; k < NPW; ++k) {
            if (j0[k] >= endv[k]) continue;
            int cnt = endv[k] - j0[k]; if (cnt > 16) cnt = 16;
            int steps = (cnt + 1) >> 1;
            for (int t = 0; t < steps; ++t) {
                int e = 2 * t + g;
                float pe = __shfl(pK[k], e * 4 + hd);
                int   se = __shfl(sK[k], e * 4);
                unsigned row = (se < 0) ? 0u : (unsigned)se;
                unsigned u = *(const unsigned*)&hbf[row * HD + 2 * c];
                accL[k] = fmaf(pe, bf16_to_f32((unsigned short)(u & 0xffffu)), accL[k]);
                accH[k] = fmaf(pe, bf16_to_f32((unsigned short)(u >> 16)),     accH[k]);
            }
            j0[k] += 16;
        }
    }

    const float2 bl = ((const float2*)bias)[c];
    #pragma unroll
    for (int k = 0; k < NPW; ++k) {
        int nk = n0 + k;
        if (nk >= N_NODES) continue;
        float l   = __shfl(l_p[k], hd);
        float inv = (l > 0.f) ? 1.f / l : 0.f;
        float vL = accL[k] + __shfl_xor(accL[k], 32);
        float vH = accH[k] + __shfl_xor(accH[k], 32);
        if (lane < 32) {
            float2 v = make_float2(vL * inv + bl.x, vH * inv + bl.y);
            *(float2*)&out[nk * HD + 2 * c] = v;
        }
    }
}

// ---------------------------------------------------------------------------
// Launch
// ---------------------------------------------------------------------------
extern "C" void kernel_launch(void* const* d_in, const int* in_sizes, int n_in,
                              void* d_out, int out_size, void* d_ws, size_t ws_size,
                              hipStream_t stream) {
    const float* feat   = (const float*)d_in[0];
    const float* W      = (const float*)d_in[1];
    const float* attn_l = (const float*)d_in[2];
    const float* attn_r = (const float*)d_in[3];
    const float* bias   = (const float*)d_in[4];
    const int*   src    = (const int*)d_in[5];
    const int*   dst    = (const int*)d_in[6];
    float* out = (float*)d_out;

    // ws (~22 MB): hbf [N*64 bf16] | el [N*4 f32] | er [N*4] | deg [N] | cend [N]
    //              | edges [E] | counts [MAT] | bsums [NB]
    unsigned short* hbf = (unsigned short*)d_ws;
    float* el    = (float*)(hbf + (size_t)N_NODES * HD);
    float* er    = el + (size_t)N_NODES * HEADS;
    int*   deg    = (int*)(er + (size_t)N_NODES * HEADS);
    int*   cend   = deg + N_NODES;
    int*   edges  = cend + N_NODES;
    int*   counts = edges + N_EDGES;
    int*   bsums  = counts + MAT;

    // 1) projection + fused el/er (h stored bf16)
    k_gemm_fused<<<(N_NODES + 127) / 128, 256, 0, stream>>>(feat, W, attn_l, attn_r,
                                                            hbf, el, er);
    // 2) CSR build: two-level counting sort (scanC folded into consumers)
    k_count<<<PART_BLOCKS, 256, 0, stream>>>(dst, counts);
    k_scanA<<<NB, 256, 0, stream>>>(counts, bsums);
    k_scanB<<<1, 512, 0, stream>>>(bsums);
    k_partition<<<PART_BLOCKS, 256, 0, stream>>>(src, dst, counts, bsums, edges);
    k_bucket_sort<<<NB, 256, 0, stream>>>(bsums, edges, deg, cend);
    // 3) fused softmax + aggregation, 4 nodes per wave
    const int nodes_per_block = 4 * NPW;   // 4 waves x 4 nodes
    k_aggregate_csr<<<(N_NODES + nodes_per_block - 1) / nodes_per_block, 256, 0, stream>>>(
        edges, cend, deg, hbf, el, er, bias, out);
}